// Round 4
// baseline (177.021 us; speedup 1.0000x reference)
//
#include <hip/hip_runtime.h>

#define CC 8
#define HH 256
#define WW 512
#define KK 9

// LDS-free variant. The LDS in R0-R3 provided only cross-lane redistribution
// of the shifted x window (no temporal reuse: each input row feeds exactly one
// tap-row per block). The window x[w0-4 .. w0+7] is 16B-aligned (w0-4 is a
// multiple of 4 floats), so each lane loads it directly as 3 coalesced float4;
// the 3x inter-lane overlap is absorbed by L1 lines. Deletes all ds_write/
// ds_read ops and the staging write->read lgkmcnt dependency.
__global__ __launch_bounds__(256, 4) void dynfilter_kernel(
    const float* __restrict__ x,
    const float* __restrict__ filt,
    const float* __restrict__ fbias,
    float* __restrict__ out)
{
    const int tid  = threadIdx.x;
    const int wv   = tid >> 6;          // wave -> channels {2wv, 2wv+1}
    const int lane = tid & 63;

    // XCD-aware bijective swizzle (nwg=1024 % 8 == 0): each XCD gets a
    // contiguous band (one n, 64-h band, both segs) -> x rows L2-resident.
    const int bid0 = blockIdx.x;
    const int bid  = ((bid0 & 7) << 7) | (bid0 >> 3);

    const int seg = bid & 1;
    const int h   = (bid >> 1) & 255;
    const int n   = bid >> 9;

    const int w0 = seg * 256 + (lane << 2);   // 4 px per lane

    const size_t HW = (size_t)HH * WW;
    const int c0 = wv << 1;

    // base pointers at float index (w0 - 4) of each channel's image
    const float* xb0  = x + (size_t)(n * CC + c0)     * HW + (w0 - 4);
    const float* xb1  = x + (size_t)(n * CC + c0 + 1) * HW + (w0 - 4);
    const float* fptr = filt + ((size_t)(n * 81) * HH + h) * WW + w0;

    // chunk validity: chunks at float-w {w0-4, w0, w0+4}; width 512 is a
    // multiple of 4, so each 4-float chunk is fully in or fully out.
    const bool ok0 = (unsigned)(w0 - 4) < (unsigned)WW;   // only lane0/seg0 fails
    const bool ok2 = (unsigned)(w0 + 4) < (unsigned)WW;   // only lane63/seg1 fails

    float acc0[4], acc1[4];
    {
        const float4 b4 = *(const float4*)(fbias + ((size_t)(n * HH + h)) * WW + w0);
        acc0[0]=b4.x; acc0[1]=b4.y; acc0[2]=b4.z; acc0[3]=b4.w;
        acc1[0]=b4.x; acc1[1]=b4.y; acc1[2]=b4.z; acc1[3]=b4.w;
    }

    // CRITICAL: compiler auto-unrolls trip-count-9 loops, then hoists all 81
    // filter loads -> 256 VGPR + scratch spill. unroll(disable) is the fix.
    #pragma clang loop unroll(disable)
    for (int i = 0; i < KK; ++i) {
        const int hh = h - 4 + i;
        const bool rowok = (unsigned)hh < (unsigned)HH;
        const size_t ro = (size_t)hh * WW;

        const float4 z = make_float4(0.f, 0.f, 0.f, 0.f);

        // x window: 2 channels x 3 aligned float4 (12 floats each)
        float4 u00 = (rowok && ok0) ? *(const float4*)(xb0 + ro)     : z;
        float4 u01 =  rowok         ? *(const float4*)(xb0 + ro + 4) : z;
        float4 u02 = (rowok && ok2) ? *(const float4*)(xb0 + ro + 8) : z;
        float4 u10 = (rowok && ok0) ? *(const float4*)(xb1 + ro)     : z;
        float4 u11 =  rowok         ? *(const float4*)(xb1 + ro + 4) : z;
        float4 u12 = (rowok && ok2) ? *(const float4*)(xb1 + ro + 8) : z;

        // filter taps for row i: 9 coalesced float4 loads (4 px per lane)
        float4 f[9];
        {
            const float* fi = fptr + (size_t)i * KK * HW;
            #pragma unroll
            for (int j = 0; j < 9; ++j) f[j] = *(const float4*)(fi + (size_t)j * HW);
        }

        float v0[12], v1[12];
        v0[0]=u00.x; v0[1]=u00.y; v0[2] =u00.z; v0[3] =u00.w;
        v0[4]=u01.x; v0[5]=u01.y; v0[6] =u01.z; v0[7] =u01.w;
        v0[8]=u02.x; v0[9]=u02.y; v0[10]=u02.z; v0[11]=u02.w;
        v1[0]=u10.x; v1[1]=u10.y; v1[2] =u10.z; v1[3] =u10.w;
        v1[4]=u11.x; v1[5]=u11.y; v1[6] =u11.z; v1[7] =u11.w;
        v1[8]=u12.x; v1[9]=u12.y; v1[10]=u12.z; v1[11]=u12.w;

        // 72 FMAs (2 ch x 4 px x 9 taps)
        #pragma unroll
        for (int j = 0; j < 9; ++j) {
            acc0[0] = fmaf(f[j].x, v0[j+0], acc0[0]);
            acc0[1] = fmaf(f[j].y, v0[j+1], acc0[1]);
            acc0[2] = fmaf(f[j].z, v0[j+2], acc0[2]);
            acc0[3] = fmaf(f[j].w, v0[j+3], acc0[3]);
            acc1[0] = fmaf(f[j].x, v1[j+0], acc1[0]);
            acc1[1] = fmaf(f[j].y, v1[j+1], acc1[1]);
            acc1[2] = fmaf(f[j].z, v1[j+2], acc1[2]);
            acc1[3] = fmaf(f[j].w, v1[j+3], acc1[3]);
        }
    }

    {
        const float4 o0 = make_float4(acc0[0], acc0[1], acc0[2], acc0[3]);
        const float4 o1 = make_float4(acc1[0], acc1[1], acc1[2], acc1[3]);
        *(float4*)(out + ((size_t)(n * CC + c0)     * HH + h) * WW + w0) = o0;
        *(float4*)(out + ((size_t)(n * CC + c0 + 1) * HH + h) * WW + w0) = o1;
    }
}

extern "C" void kernel_launch(void* const* d_in, const int* in_sizes, int n_in,
                              void* d_out, int out_size, void* d_ws, size_t ws_size,
                              hipStream_t stream) {
    const float* x  = (const float*)d_in[0];
    const float* f  = (const float*)d_in[1];
    const float* fb = (const float*)d_in[2];
    float* o = (float*)d_out;
    hipLaunchKernelGGL(dynfilter_kernel, dim3(1024), dim3(256), 0, stream,
                       x, f, fb, o);
}